// Round 1
// baseline (1441.710 us; speedup 1.0000x reference)
//
#include <hip/hip_runtime.h>
#include <stdint.h>

#define B_DIM 8192
#define D_DIM 1024
#define H_DIM 2048
#define E_DIM 8
#define C_DIM 1024

typedef _Float16 f16x8 __attribute__((ext_vector_type(8)));
typedef float f32x4 __attribute__((ext_vector_type(4)));

__device__ __forceinline__ void store_val(float* p, float v) { *p = v; }
__device__ __forceinline__ void store_val(_Float16* p, float v) { *p = (_Float16)v; }

__device__ __forceinline__ void async_cp16(const void* g, void* l) {
  __builtin_amdgcn_global_load_lds((const __attribute__((address_space(1))) void*)g,
                                   (__attribute__((address_space(3))) void*)l, 16, 0, 0);
}

// ---------------------------------------------------------------------------
// 128x128 tile kernel (m97 structure) — kept for the small GEMMs (router, fold).
// ---------------------------------------------------------------------------
template <bool RELU, bool BIAS, typename OUT_T>
__global__ void __launch_bounds__(256) gemm_bt(
    const _Float16* __restrict__ A, long aZ,
    const _Float16* __restrict__ Bt, long bZ,
    const float* __restrict__ bias, long biasZ,
    OUT_T* __restrict__ out, long outZ,
    int K, long rs)
{
  __shared__ _Float16 ldsA[128 * 64];
  __shared__ _Float16 ldsB[128 * 64];

  const int z = blockIdx.z;
  A   += (size_t)z * aZ;
  Bt  += (size_t)z * bZ;
  if (BIAS) bias += (size_t)z * biasZ;
  out += (size_t)z * outZ;

  const int tid  = threadIdx.x;
  const int wave = tid >> 6;
  const int lane = tid & 63;
  const int q    = lane >> 4;
  const int l16  = lane & 15;
  const int l8   = lane >> 3;
  const int l7   = lane & 7;

  const int m0   = blockIdx.y * 128;
  const int n0   = blockIdx.x * 128;
  const int wrow = (wave >> 1) * 64;
  const int wcol = (wave & 1) * 64;

  const int swz_st = ((l7 ^ l8) << 3);
  const _Float16* pa[4];
  const _Float16* pb[4];
#pragma unroll
  for (int i = 0; i < 4; ++i) {
    int ci = wave * 4 + i;
    pa[i] = A  + (size_t)(m0 + ci * 8 + l8) * K + swz_st;
    pb[i] = Bt + (size_t)(n0 + ci * 8 + l8) * K + swz_st;
  }

  int a_off[2][4], b_off[2][4];
#pragma unroll
  for (int kk = 0; kk < 2; ++kk) {
#pragma unroll
    for (int r = 0; r < 4; ++r) {
      int sw = ((kk * 4 + q) ^ (l16 & 7)) << 4;
      a_off[kk][r] = (wrow + r * 16 + l16) * 128 + sw;
      b_off[kk][r] = (wcol + r * 16 + l16) * 128 + sw;
    }
  }

  f32x4 acc[4][4];
#pragma unroll
  for (int r = 0; r < 4; ++r)
#pragma unroll
    for (int c = 0; c < 4; ++c)
      acc[r][c] = (f32x4){0.f, 0.f, 0.f, 0.f};

  const char* lAc = (const char*)ldsA;
  const char* lBc = (const char*)ldsB;

  for (int kt = 0; kt < K; kt += 64) {
    __syncthreads();
#pragma unroll
    for (int i = 0; i < 4; ++i) {
      int ci = wave * 4 + i;
      async_cp16(pa[i], ldsA + ci * 512);
      async_cp16(pb[i], ldsB + ci * 512);
      pa[i] += 64;
      pb[i] += 64;
    }
    __syncthreads();
#pragma unroll
    for (int kk = 0; kk < 2; ++kk) {
      f16x8 af[4], bfv[4];
#pragma unroll
      for (int r = 0; r < 4; ++r) af[r]  = *(const f16x8*)(lAc + a_off[kk][r]);
#pragma unroll
      for (int c = 0; c < 4; ++c) bfv[c] = *(const f16x8*)(lBc + b_off[kk][c]);
#pragma unroll
      for (int r = 0; r < 4; ++r)
#pragma unroll
        for (int c = 0; c < 4; ++c)
          acc[r][c] = __builtin_amdgcn_mfma_f32_16x16x32_f16(af[r], bfv[c], acc[r][c], 0, 0, 0);
    }
  }

#pragma unroll
  for (int c = 0; c < 4; ++c) {
    int col = n0 + wcol + c * 16 + l16;
    float bv = BIAS ? bias[col] : 0.f;
#pragma unroll
    for (int r = 0; r < 4; ++r) {
      int row = m0 + wrow + r * 16 + q * 4;
      f32x4 v = acc[r][c];
#pragma unroll
      for (int i = 0; i < 4; ++i) {
        float xv = v[i] + bv;
        if (RELU) xv = fmaxf(xv, 0.f);
        store_val(out + (size_t)(row + i) * rs + col, xv);
      }
    }
  }
}

// ---------------------------------------------------------------------------
// 256x256 tile, BK=64, 8 waves (2Mx4N), 4 phases per K-tile, counted vmcnt
// (T2+T3+T4+T5 + T1). Per wave: 128x64 output = 8x4 16x16 frags.
// LDS: 2 buffers x (A 256x64 + B 256x64) f16 = 128 KiB.
// Schedule per K-tile t (buf b = t&1):
//   p0: ds_read A rows 0-1 + ALL B frags; stage (t+1).A-lo -> buf b^1
//   p1: ds_read A rows 2-3;               stage (t+1).A-hi -> buf b^1
//   p2: ds_read A rows 4-5;               stage (t+2).B-lo -> buf b   (B slots
//   p3: ds_read A rows 6-7;               stage (t+2).B-hi -> buf b    free after p0)
//   each phase: barrier; lgkmcnt(0); sched_barrier; setprio(1); 16 MFMA; setprio(0); barrier
//   p3 extra: vmcnt(4) (t<NT-2) / vmcnt(0) (t>=NT-2) before final barrier
// ---------------------------------------------------------------------------
template <bool RELU, bool BIAS, typename OUT_T>
__global__ void __launch_bounds__(512) gemm256(
    const _Float16* __restrict__ A, long aZ,
    const _Float16* __restrict__ Bt, long bZ,
    const float* __restrict__ bias, long biasZ,
    OUT_T* __restrict__ out, long outZ,
    int K, long rs)
{
  __shared__ _Float16 ldsA[2 * 256 * 64];
  __shared__ _Float16 ldsB[2 * 256 * 64];

  const int z = blockIdx.z;
  A   += (size_t)z * aZ;
  Bt  += (size_t)z * bZ;
  if (BIAS) bias += (size_t)z * biasZ;
  out += (size_t)z * outZ;

  // T1: bijective XCD swizzle of (x,y); all our grids have nwg % 8 == 0.
  const int nwg = gridDim.x * gridDim.y;
  const int wg  = blockIdx.y * gridDim.x + blockIdx.x;
  const int sw  = (wg & 7) * (nwg >> 3) + (wg >> 3);
  const int bx  = sw % gridDim.x;
  const int by  = sw / gridDim.x;

  const int tid  = threadIdx.x;
  const int wave = tid >> 6;
  const int lane = tid & 63;
  const int q    = lane >> 4;
  const int l16  = lane & 15;
  const int l8   = lane >> 3;
  const int l7   = lane & 7;

  const int m0   = by * 256;
  const int n0   = bx * 256;
  const int wm   = wave >> 2;   // 0..1 -> 128-row slab of A-tile
  const int wn   = wave & 3;    // 0..3 -> 64-col slab of B-tile
  const int wrow = wm * 128;
  const int wcol = wn * 64;

  // Staging: thread covers chunk (wave*2+i) of each 128-row half; 8 rows/chunk.
  // Pre-swizzled global source + linear LDS dest (global_load_lds writes
  // base + lane*16); slot j of row r holds k-chunk j^(r&7).
  const int swz_st = ((l7 ^ l8) << 3);
  const _Float16* paB = A  + (size_t)(m0 + wave * 16 + l8) * K + swz_st;
  const _Float16* pbB = Bt + (size_t)(n0 + wave * 16 + l8) * K + swz_st;

  int a_base[2], b_base[2];
#pragma unroll
  for (int kk = 0; kk < 2; ++kk) {
    int swr = (((kk * 4 + q) ^ (l16 & 7)) << 4);
    a_base[kk] = (wrow + l16) * 128 + swr;
    b_base[kk] = (wcol + l16) * 128 + swr;
  }

  f32x4 acc[8][4];
#pragma unroll
  for (int r = 0; r < 8; ++r)
#pragma unroll
    for (int c = 0; c < 4; ++c)
      acc[r][c] = (f32x4){0.f, 0.f, 0.f, 0.f};

  const char* lA = (const char*)ldsA;
  const char* lB = (const char*)ldsB;
  const int NT = K >> 6;

#define STAGE_A(buf, h, tt)                                                          \
  {                                                                                  \
    _Pragma("unroll")                                                                \
    for (int i_ = 0; i_ < 2; ++i_)                                                   \
      async_cp16(paB + (size_t)((h) * 128 + i_ * 8) * K + (tt) * 64,                 \
                 (void*)(ldsA + (buf) * 16384 + (h) * 8192 + (wave * 2 + i_) * 512)); \
  }
#define STAGE_B(buf, h, tt)                                                          \
  {                                                                                  \
    _Pragma("unroll")                                                                \
    for (int i_ = 0; i_ < 2; ++i_)                                                   \
      async_cp16(pbB + (size_t)((h) * 128 + i_ * 8) * K + (tt) * 64,                 \
                 (void*)(ldsB + (buf) * 16384 + (h) * 8192 + (wave * 2 + i_) * 512)); \
  }

  // Prologue: tile0 fully + tile1's B halves (12 loads); wait tile0 (allow
  // newest 4 = t1.B in flight); barrier makes it collective.
  STAGE_A(0, 0, 0) STAGE_A(0, 1, 0) STAGE_B(0, 0, 0) STAGE_B(0, 1, 0)
  STAGE_B(1, 0, 1) STAGE_B(1, 1, 1)
  asm volatile("s_waitcnt vmcnt(4)" ::: "memory");
  __builtin_amdgcn_s_barrier();

  for (int t = 0; t < NT; ++t) {
    const int bofs = (t & 1) * 32768;  // byte offset of current buffer
    f16x8 bf[4][2];
#pragma unroll
    for (int p = 0; p < 4; ++p) {
      // ds-load register subtile: A rows 2p,2p+1; all B frags at p0 (held).
      f16x8 af[2][2];
#pragma unroll
      for (int rr = 0; rr < 2; ++rr)
#pragma unroll
        for (int kk = 0; kk < 2; ++kk)
          af[rr][kk] = *(const f16x8*)(lA + bofs + a_base[kk] + (2 * p + rr) * 2048);
      if (p == 0) {
#pragma unroll
        for (int c = 0; c < 4; ++c)
#pragma unroll
          for (int kk = 0; kk < 2; ++kk)
            bf[c][kk] = *(const f16x8*)(lB + bofs + b_base[kk] + c * 2048);
      }
      // stage exactly one half-tile (2 loads/thread), into a slot freed
      // >= 2 barriers ago.
      if (p == 0 && t + 1 < NT) STAGE_A((t + 1) & 1, 0, t + 1)
      if (p == 1 && t + 1 < NT) STAGE_A((t + 1) & 1, 1, t + 1)
      if (p == 2 && t + 2 < NT) STAGE_B(t & 1, 0, t + 2)
      if (p == 3 && t + 2 < NT) STAGE_B(t & 1, 1, t + 2)

      __builtin_amdgcn_s_barrier();
      asm volatile("s_waitcnt lgkmcnt(0)" ::: "memory");
      __builtin_amdgcn_sched_barrier(0);
      __builtin_amdgcn_s_setprio(1);
#pragma unroll
      for (int c = 0; c < 4; ++c)
#pragma unroll
        for (int rr = 0; rr < 2; ++rr)
#pragma unroll
          for (int kk = 0; kk < 2; ++kk)
            acc[2 * p + rr][c] = __builtin_amdgcn_mfma_f32_16x16x32_f16(
                af[rr][kk], bf[c][kk], acc[2 * p + rr][c], 0, 0, 0);
      __builtin_amdgcn_s_setprio(0);
      if (p == 3) {
        // counted vmcnt: tile t+1 must be landed; t+2's B halves (4 loads)
        // may stay in flight. Drain fully only before the last tile.
        if (t < NT - 2) asm volatile("s_waitcnt vmcnt(4)" ::: "memory");
        else            asm volatile("s_waitcnt vmcnt(0)" ::: "memory");
      }
      __builtin_amdgcn_s_barrier();
    }
  }
#undef STAGE_A
#undef STAGE_B

  // Epilogue: D[row=q*4+i][col=l16] per 16x16 frag (verified C/D layout).
#pragma unroll
  for (int c = 0; c < 4; ++c) {
    int col = n0 + wcol + c * 16 + l16;
    float bv = BIAS ? bias[col] : 0.f;
#pragma unroll
    for (int r = 0; r < 8; ++r) {
      int row = m0 + wrow + r * 16 + q * 4;
      f32x4 v = acc[r][c];
#pragma unroll
      for (int i = 0; i < 4; ++i) {
        float xv = v[i] + bv;
        if (RELU) xv = fmaxf(xv, 0.f);
        store_val(out + (size_t)(row + i) * rs + col, xv);
      }
    }
  }
}

// ---------------------------------------------------------------------------
__global__ void cast_f32_f16(const float* __restrict__ in, _Float16* __restrict__ out, int n) {
  int i = (blockIdx.x * blockDim.x + threadIdx.x) * 4;
  if (i >= n) return;
  float4 v = *(const float4*)(in + i);
  union { _Float16 h[4]; uint2 u; } r;
  r.h[0] = (_Float16)v.x; r.h[1] = (_Float16)v.y;
  r.h[2] = (_Float16)v.z; r.h[3] = (_Float16)v.w;
  *(uint2*)(out + i) = r.u;
}

// in [R][Cn] fp32 (batched over z) -> out [Cn][R] fp16
__global__ void transpose_cast(const float* __restrict__ in, _Float16* __restrict__ out,
                               int R, int Cn) {
  __shared__ float tile[32][33];
  in  += (size_t)blockIdx.z * R * Cn;
  out += (size_t)blockIdx.z * R * Cn;
  int c0 = blockIdx.x * 32, r0 = blockIdx.y * 32;
  int tx = threadIdx.x, ty = threadIdx.y;
#pragma unroll
  for (int i = ty; i < 32; i += 8)
    tile[i][tx] = in[(size_t)(r0 + i) * Cn + c0 + tx];
  __syncthreads();
#pragma unroll
  for (int i = ty; i < 32; i += 8)
    out[(size_t)(c0 + i) * R + r0 + tx] = (_Float16)tile[tx][i];
}

// scores = softmax(g[B][D](f16) @ w2[D][8] + b2), one block per row.
__global__ void gate2_softmax(const _Float16* __restrict__ g, const float* __restrict__ w2,
                              const float* __restrict__ b2, float* __restrict__ scores) {
  int b = blockIdx.x;
  int t = threadIdx.x;            // 256
  int e = t & 7, slice = t >> 3;  // 8 experts x 32 slices
  const _Float16* gr = g + (size_t)b * D_DIM;
  float acc = 0.f;
  for (int d = slice; d < D_DIM; d += 32)
    acc += (float)gr[d] * w2[d * 8 + e];
  __shared__ float red[256];
  red[t] = acc;
  __syncthreads();
  for (int s = 16; s > 0; s >>= 1) {
    if (slice < s) red[t] += red[t + s * 8];
    __syncthreads();
  }
  __shared__ float sm[8];
  if (t < 8) sm[t] = red[t] + b2[t];
  __syncthreads();
  if (t == 0) {
    float mx = sm[0];
#pragma unroll
    for (int i = 1; i < 8; ++i) mx = fmaxf(mx, sm[i]);
    float ex[8], s = 0.f;
#pragma unroll
    for (int i = 0; i < 8; ++i) { ex[i] = expf(sm[i] - mx); s += ex[i]; }
    float inv = 1.f / s;
#pragma unroll
    for (int i = 0; i < 8; ++i) scores[(size_t)b * 8 + i] = ex[i] * inv;
  }
}

// bc[e][c] = cb[c] + sum_k b2[e][k] * cw[k][c]   (combined classifier bias)
__global__ void combined_bias(const float* __restrict__ b2, const float* __restrict__ cw,
                              const float* __restrict__ cb, float* __restrict__ bc) {
  int e  = blockIdx.y;
  int cl = threadIdx.x & 63;
  int c  = blockIdx.x * 64 + cl;
  int ks = threadIdx.x >> 6;  // 4 k-slices
  float acc = 0.f;
  for (int k = ks; k < H_DIM; k += 4)
    acc += b2[e * H_DIM + k] * cw[(size_t)k * C_DIM + c];
  __shared__ float red[256];
  red[threadIdx.x] = acc;
  __syncthreads();
  if (ks == 0)
    bc[(size_t)e * C_DIM + c] = red[cl] + red[cl + 64] + red[cl + 128] + red[cl + 192] + cb[c];
}

// ---------------------------------------------------------------------------
extern "C" void kernel_launch(void* const* d_in, const int* in_sizes, int n_in,
                              void* d_out, int out_size, void* d_ws, size_t ws_size,
                              hipStream_t stream) {
  const float* x   = (const float*)d_in[0];
  const float* gw1 = (const float*)d_in[1];
  const float* gb1 = (const float*)d_in[2];
  const float* gw2 = (const float*)d_in[3];
  const float* gb2 = (const float*)d_in[4];
  const float* W1  = (const float*)d_in[5];
  const float* b1  = (const float*)d_in[6];
  const float* W2  = (const float*)d_in[7];
  const float* b2  = (const float*)d_in[8];
  const float* cw  = (const float*)d_in[9];
  const float* cb  = (const float*)d_in[10];

  char* ws = (char*)d_ws;
  _Float16* xb     = (_Float16*)(ws);                    // B*D        16 MB
  _Float16* g      = (_Float16*)(ws + 16777216ull);      // B*D        16 MB
  _Float16* gw1t   = (_Float16*)(ws + 33554432ull);      // D*D         2 MB
  _Float16* W1t    = (_Float16*)(ws + 35651584ull);      // E*H*D      32 MB
  _Float16* W2c    = (_Float16*)(ws + 69206016ull);      // E*H*H      64 MB (cast, NOT transposed)
  _Float16* cwt    = (_Float16*)(ws + 136314880ull);     // C*H         4 MB
  _Float16* WcombT = (_Float16*)(ws + 140509184ull);     // E*C*H      32 MB
  float*    bc     = (float*)   (ws + 174063616ull);     // E*C        32 KB
  _Float16* h_all  = (_Float16*)(ws + 174096384ull);     // E*B*H     256 MB
                                                         // total ~422 MB

  float* logits = (float*)d_out;
  float* scores = logits + (size_t)B_DIM * E_DIM * C_DIM;

  // Precision prep: casts + [N][K] weight transposes
  cast_f32_f16<<<B_DIM * D_DIM / 4 / 256, 256, 0, stream>>>(x, xb, B_DIM * D_DIM);
  transpose_cast<<<dim3(32, 32, 1), dim3(32, 8), 0, stream>>>(gw1, gw1t, D_DIM, D_DIM);
  transpose_cast<<<dim3(64, 32, 8), dim3(32, 8), 0, stream>>>(W1, W1t, D_DIM, H_DIM);
  cast_f32_f16<<<E_DIM * H_DIM * H_DIM / 4 / 256, 256, 0, stream>>>(W2, W2c, E_DIM * H_DIM * H_DIM);
  transpose_cast<<<dim3(32, 64, 1), dim3(32, 8), 0, stream>>>(cw, cwt, H_DIM, C_DIM);

  // Router
  gemm_bt<true, true, _Float16><<<dim3(8, 64, 1), 256, 0, stream>>>(
      xb, 0, gw1t, 0, gb1, 0, g, 0, D_DIM, (long)D_DIM);
  gate2_softmax<<<B_DIM, 256, 0, stream>>>(g, gw2, gb2, scores);

  // Classifier folding: WcombT[e][c][h'] = sum_k2 Wc[k2][c] * W2[e][h'][k2]
  gemm_bt<false, false, _Float16><<<dim3(16, 8, 8), 256, 0, stream>>>(
      cwt, 0, W2c, (long)H_DIM * H_DIM, nullptr, 0,
      WcombT, (long)C_DIM * H_DIM, H_DIM, (long)H_DIM);
  combined_bias<<<dim3(C_DIM / 64, E_DIM), 256, 0, stream>>>(b2, cw, cb, bc);

  // Layer 1, all experts batched: h_all[e] = relu(x @ W1[e] + b1[e])  [256^2 8-phase]
  gemm256<true, true, _Float16><<<dim3(8, 32, 8), 512, 0, stream>>>(
      xb, 0, W1t, (long)H_DIM * D_DIM, b1, (long)H_DIM,
      h_all, (long)B_DIM * H_DIM, D_DIM, (long)H_DIM);

  // Fused layer2+classifier: logits[:,e,:] = h_all[e] @ Wcomb[e] + bc[e]  [256^2 8-phase]
  gemm256<false, true, float><<<dim3(4, 32, 8), 512, 0, stream>>>(
      h_all, (long)B_DIM * H_DIM, WcombT, (long)C_DIM * H_DIM, bc, (long)C_DIM,
      logits, (long)C_DIM, H_DIM, (long)(E_DIM * C_DIM));
}

// Round 2
// 1405.782 us; speedup vs baseline: 1.0256x; 1.0256x over previous
//
#include <hip/hip_runtime.h>
#include <stdint.h>

#define B_DIM 8192
#define D_DIM 1024
#define H_DIM 2048
#define E_DIM 8
#define C_DIM 1024

typedef _Float16 f16x8 __attribute__((ext_vector_type(8)));
typedef float f32x4 __attribute__((ext_vector_type(4)));

__device__ __forceinline__ void store_val(float* p, float v) { *p = v; }
__device__ __forceinline__ void store_val(_Float16* p, float v) { *p = (_Float16)v; }

__device__ __forceinline__ void async_cp16(const void* g, void* l) {
  __builtin_amdgcn_global_load_lds((const __attribute__((address_space(1))) void*)g,
                                   (__attribute__((address_space(3))) void*)l, 16, 0, 0);
}

// ---------------------------------------------------------------------------
// 128x128 tile kernel (m97 structure) — kept for the router GEMM only.
// ---------------------------------------------------------------------------
template <bool RELU, bool BIAS, typename OUT_T>
__global__ void __launch_bounds__(256) gemm_bt(
    const _Float16* __restrict__ A, long aZ,
    const _Float16* __restrict__ Bt, long bZ,
    const float* __restrict__ bias, long biasZ,
    OUT_T* __restrict__ out, long outZ,
    int K, long rs)
{
  __shared__ _Float16 ldsA[128 * 64];
  __shared__ _Float16 ldsB[128 * 64];

  const int z = blockIdx.z;
  A   += (size_t)z * aZ;
  Bt  += (size_t)z * bZ;
  if (BIAS) bias += (size_t)z * biasZ;
  out += (size_t)z * outZ;

  const int tid  = threadIdx.x;
  const int wave = tid >> 6;
  const int lane = tid & 63;
  const int q    = lane >> 4;
  const int l16  = lane & 15;
  const int l8   = lane >> 3;
  const int l7   = lane & 7;

  const int m0   = blockIdx.y * 128;
  const int n0   = blockIdx.x * 128;
  const int wrow = (wave >> 1) * 64;
  const int wcol = (wave & 1) * 64;

  const int swz_st = ((l7 ^ l8) << 3);
  const _Float16* pa[4];
  const _Float16* pb[4];
#pragma unroll
  for (int i = 0; i < 4; ++i) {
    int ci = wave * 4 + i;
    pa[i] = A  + (size_t)(m0 + ci * 8 + l8) * K + swz_st;
    pb[i] = Bt + (size_t)(n0 + ci * 8 + l8) * K + swz_st;
  }

  int a_off[2][4], b_off[2][4];
#pragma unroll
  for (int kk = 0; kk < 2; ++kk) {
#pragma unroll
    for (int r = 0; r < 4; ++r) {
      int sw = ((kk * 4 + q) ^ (l16 & 7)) << 4;
      a_off[kk][r] = (wrow + r * 16 + l16) * 128 + sw;
      b_off[kk][r] = (wcol + r * 16 + l16) * 128 + sw;
    }
  }

  f32x4 acc[4][4];
#pragma unroll
  for (int r = 0; r < 4; ++r)
#pragma unroll
    for (int c = 0; c < 4; ++c)
      acc[r][c] = (f32x4){0.f, 0.f, 0.f, 0.f};

  const char* lAc = (const char*)ldsA;
  const char* lBc = (const char*)ldsB;

  for (int kt = 0; kt < K; kt += 64) {
    __syncthreads();
#pragma unroll
    for (int i = 0; i < 4; ++i) {
      int ci = wave * 4 + i;
      async_cp16(pa[i], ldsA + ci * 512);
      async_cp16(pb[i], ldsB + ci * 512);
      pa[i] += 64;
      pb[i] += 64;
    }
    __syncthreads();
#pragma unroll
    for (int kk = 0; kk < 2; ++kk) {
      f16x8 af[4], bfv[4];
#pragma unroll
      for (int r = 0; r < 4; ++r) af[r]  = *(const f16x8*)(lAc + a_off[kk][r]);
#pragma unroll
      for (int c = 0; c < 4; ++c) bfv[c] = *(const f16x8*)(lBc + b_off[kk][c]);
#pragma unroll
      for (int r = 0; r < 4; ++r)
#pragma unroll
        for (int c = 0; c < 4; ++c)
          acc[r][c] = __builtin_amdgcn_mfma_f32_16x16x32_f16(af[r], bfv[c], acc[r][c], 0, 0, 0);
    }
  }

#pragma unroll
  for (int c = 0; c < 4; ++c) {
    int col = n0 + wcol + c * 16 + l16;
    float bv = BIAS ? bias[col] : 0.f;
#pragma unroll
    for (int r = 0; r < 4; ++r) {
      int row = m0 + wrow + r * 16 + q * 4;
      f32x4 v = acc[r][c];
#pragma unroll
      for (int i = 0; i < 4; ++i) {
        float xv = v[i] + bv;
        if (RELU) xv = fmaxf(xv, 0.f);
        store_val(out + (size_t)(row + i) * rs + col, xv);
      }
    }
  }
}

// ---------------------------------------------------------------------------
// 256x256 tile, BK=64, 8 waves (2Mx4N), kk-split 4-phase K-loop, ONE barrier
// per phase (post-MFMA), counted vmcnt, templated K (T1+T2+T3+T4+T5).
// Phases p=(kk,h): kk=p>>1 selects K-half, h=p&1 selects 4-row A block.
//   reads/phase: 8 (h==0: 4 B + 4 A) or 4 (h==1: 4 A); 16 indep MFMA/phase.
// Stage: p0/p1 -> A(t+1) halves into buf^1; p3 -> B(t+2) into buf (B(t)'s
//   cells last read at p2). Safety: a wave reaches stage(q) only after
//   barrier(q-1), which all waves reach only after their lgkmcnt(0) drained
//   (pinned explicitly before each barrier) => phase-(q-1) reads complete.
// vmcnt(4) at p3: drains B(t+1)+A(t+1) (needed next tile), keeps B(t+2)'s
//   4 loads in flight across the barrier. vmcnt(0) only for the last 2 tiles.
// ---------------------------------------------------------------------------
template <bool RELU, bool BIAS, typename OUT_T, int K_CT>
__global__ void __launch_bounds__(512) gemm256(
    const _Float16* __restrict__ A, long aZ,
    const _Float16* __restrict__ Bt, long bZ,
    const float* __restrict__ bias, long biasZ,
    OUT_T* __restrict__ out, long outZ, long rs)
{
  constexpr int NT = K_CT / 64;
  __shared__ _Float16 ldsA[2 * 256 * 64];
  __shared__ _Float16 ldsB[2 * 256 * 64];

  const int z = blockIdx.z;
  A   += (size_t)z * aZ;
  Bt  += (size_t)z * bZ;
  if (BIAS) bias += (size_t)z * biasZ;
  out += (size_t)z * outZ;

  // T1: bijective XCD swizzle of (x,y); all grids here have nwg % 8 == 0.
  const int nwg = gridDim.x * gridDim.y;
  const int wg  = blockIdx.y * gridDim.x + blockIdx.x;
  const int sw  = (wg & 7) * (nwg >> 3) + (wg >> 3);
  const int bx  = sw % gridDim.x;
  const int by  = sw / gridDim.x;

  const int tid  = threadIdx.x;
  const int wave = tid >> 6;
  const int lane = tid & 63;
  const int q    = lane >> 4;
  const int l16  = lane & 15;
  const int l8   = lane >> 3;
  const int l7   = lane & 7;

  const int m0   = by * 256;
  const int n0   = bx * 256;
  const int wm   = wave >> 2;   // 0..1 -> 128-row slab of A-tile
  const int wn   = wave & 3;    // 0..3 -> 64-col slab of B-tile
  const int wrow = wm * 128;
  const int wcol = wn * 64;

  // Pre-swizzled global source + linear LDS dest; slot j of row r holds
  // k-chunk j^(r&7).
  const int swz_st = ((l7 ^ l8) << 3);
  const _Float16* paB = A  + (size_t)(m0 + wave * 16 + l8) * K_CT + swz_st;
  const _Float16* pbB = Bt + (size_t)(n0 + wave * 16 + l8) * K_CT + swz_st;

  int a_base[2], b_base[2];
#pragma unroll
  for (int kk = 0; kk < 2; ++kk) {
    int swr = (((kk * 4 + q) ^ (l16 & 7)) << 4);
    a_base[kk] = (wrow + l16) * 128 + swr;
    b_base[kk] = (wcol + l16) * 128 + swr;
  }

  f32x4 acc[8][4];
#pragma unroll
  for (int r = 0; r < 8; ++r)
#pragma unroll
    for (int c = 0; c < 4; ++c)
      acc[r][c] = (f32x4){0.f, 0.f, 0.f, 0.f};

  const char* lA = (const char*)ldsA;
  const char* lB = (const char*)ldsB;

  // bufe = element offset of target buffer (0 / 16384); hh = 128-row half.
  // (hh*128)*K_CT folds to an immediate (K_CT is a template constant).
#define STAGE_A(bufe, hh, ptr)                                                        \
  {                                                                                   \
    _Pragma("unroll")                                                                 \
    for (int i_ = 0; i_ < 2; ++i_)                                                    \
      async_cp16((ptr) + (size_t)((hh) * 128 + i_ * 8) * K_CT,                        \
                 (void*)(ldsA + (bufe) + (hh) * 8192 + (wave * 2 + i_) * 512));       \
  }
#define STAGE_B(bufe, hh, ptr)                                                        \
  {                                                                                   \
    _Pragma("unroll")                                                                 \
    for (int i_ = 0; i_ < 2; ++i_)                                                    \
      async_cp16((ptr) + (size_t)((hh) * 128 + i_ * 8) * K_CT,                        \
                 (void*)(ldsB + (bufe) + (hh) * 8192 + (wave * 2 + i_) * 512));       \
  }

  // Prologue: tile0 A+B, tile1 B (12 loads); vmcnt(4) keeps tile1-B in flight.
  STAGE_A(0, 0, paB) STAGE_A(0, 1, paB)
  STAGE_B(0, 0, pbB) STAGE_B(0, 1, pbB)
  STAGE_B(16384, 0, pbB + 64) STAGE_B(16384, 1, pbB + 64)
  asm volatile("s_waitcnt vmcnt(4)" ::: "memory");
  __builtin_amdgcn_s_barrier();

  const _Float16* pa_t = paB + 64;   // -> tile t+1
  const _Float16* pb_t = pbB + 128;  // -> tile t+2

  for (int t = 0; t < NT; ++t) {
    const int bofs  = (t & 1) * 32768;        // byte offset, current buffer
    const int nbufe = ((t + 1) & 1) * 16384;  // elem offset, A target buffer
    const int cbufe = (t & 1) * 16384;        // elem offset, B(t+2) target
    f16x8 bf[4];
#pragma unroll
    for (int p = 0; p < 4; ++p) {
      const int kk = p >> 1, h = p & 1;
      if (h == 0) {
#pragma unroll
        for (int c = 0; c < 4; ++c)
          bf[c] = *(const f16x8*)(lB + bofs + b_base[kk] + c * 2048);
      }
      f16x8 af[4];
#pragma unroll
      for (int r = 0; r < 4; ++r)
        af[r] = *(const f16x8*)(lA + bofs + a_base[kk] + (h * 4 + r) * 2048);

      if (p == 0 && t + 1 < NT) STAGE_A(nbufe, 0, pa_t)
      if (p == 1 && t + 1 < NT) STAGE_A(nbufe, 1, pa_t)
      if (p == 3 && t + 2 < NT) { STAGE_B(cbufe, 0, pb_t) STAGE_B(cbufe, 1, pb_t) }

      __builtin_amdgcn_s_setprio(1);
#pragma unroll
      for (int c = 0; c < 4; ++c)
#pragma unroll
        for (int r = 0; r < 4; ++r)
          acc[h * 4 + r][c] = __builtin_amdgcn_mfma_f32_16x16x32_f16(
              af[r], bf[c], acc[h * 4 + r][c], 0, 0, 0);
      __builtin_amdgcn_s_setprio(0);

      // lgkmcnt(0) is ~free here (reads already consumed) but pins the
      // "reads complete before barrier" invariant the stage-hazard proof uses.
      if (p == 3) {
        if (t < NT - 2) asm volatile("s_waitcnt vmcnt(4) lgkmcnt(0)" ::: "memory");
        else            asm volatile("s_waitcnt vmcnt(0) lgkmcnt(0)" ::: "memory");
      } else {
        asm volatile("s_waitcnt lgkmcnt(0)" ::: "memory");
      }
      __builtin_amdgcn_s_barrier();
    }
    pa_t += 64;
    pb_t += 64;
  }
#undef STAGE_A
#undef STAGE_B

  // Epilogue: D[row=q*4+i][col=l16] per 16x16 frag (verified C/D layout).
#pragma unroll
  for (int c = 0; c < 4; ++c) {
    int col = n0 + wcol + c * 16 + l16;
    float bv = BIAS ? bias[col] : 0.f;
#pragma unroll
    for (int r = 0; r < 8; ++r) {
      int row = m0 + wrow + r * 16 + q * 4;
      f32x4 v = acc[r][c];
#pragma unroll
      for (int i = 0; i < 4; ++i) {
        float xv = v[i] + bv;
        if (RELU) xv = fmaxf(xv, 0.f);
        store_val(out + (size_t)(row + i) * rs + col, xv);
      }
    }
  }
}

// ---------------------------------------------------------------------------
__global__ void cast_f32_f16(const float* __restrict__ in, _Float16* __restrict__ out, int n) {
  int i = (blockIdx.x * blockDim.x + threadIdx.x) * 4;
  if (i >= n) return;
  float4 v = *(const float4*)(in + i);
  union { _Float16 h[4]; uint2 u; } r;
  r.h[0] = (_Float16)v.x; r.h[1] = (_Float16)v.y;
  r.h[2] = (_Float16)v.z; r.h[3] = (_Float16)v.w;
  *(uint2*)(out + i) = r.u;
}

// in [R][Cn] fp32 (batched over z) -> out [Cn][R] fp16
__global__ void transpose_cast(const float* __restrict__ in, _Float16* __restrict__ out,
                               int R, int Cn) {
  __shared__ float tile[32][33];
  in  += (size_t)blockIdx.z * R * Cn;
  out += (size_t)blockIdx.z * R * Cn;
  int c0 = blockIdx.x * 32, r0 = blockIdx.y * 32;
  int tx = threadIdx.x, ty = threadIdx.y;
#pragma unroll
  for (int i = ty; i < 32; i += 8)
    tile[i][tx] = in[(size_t)(r0 + i) * Cn + c0 + tx];
  __syncthreads();
#pragma unroll
  for (int i = ty; i < 32; i += 8)
    out[(size_t)(c0 + i) * R + r0 + tx] = (_Float16)tile[tx][i];
}

// scores = softmax(g[B][D](f16) @ w2[D][8] + b2), one block per row.
__global__ void gate2_softmax(const _Float16* __restrict__ g, const float* __restrict__ w2,
                              const float* __restrict__ b2, float* __restrict__ scores) {
  int b = blockIdx.x;
  int t = threadIdx.x;            // 256
  int e = t & 7, slice = t >> 3;  // 8 experts x 32 slices
  const _Float16* gr = g + (size_t)b * D_DIM;
  float acc = 0.f;
  for (int d = slice; d < D_DIM; d += 32)
    acc += (float)gr[d] * w2[d * 8 + e];
  __shared__ float red[256];
  red[t] = acc;
  __syncthreads();
  for (int s = 16; s > 0; s >>= 1) {
    if (slice < s) red[t] += red[t + s * 8];
    __syncthreads();
  }
  __shared__ float sm[8];
  if (t < 8) sm[t] = red[t] + b2[t];
  __syncthreads();
  if (t == 0) {
    float mx = sm[0];
#pragma unroll
    for (int i = 1; i < 8; ++i) mx = fmaxf(mx, sm[i]);
    float ex[8], s = 0.f;
#pragma unroll
    for (int i = 0; i < 8; ++i) { ex[i] = expf(sm[i] - mx); s += ex[i]; }
    float inv = 1.f / s;
#pragma unroll
    for (int i = 0; i < 8; ++i) scores[(size_t)b * 8 + i] = ex[i] * inv;
  }
}

// bc[e][c] = cb[c] + sum_k b2[e][k] * cw[k][c]   (combined classifier bias)
__global__ void combined_bias(const float* __restrict__ b2, const float* __restrict__ cw,
                              const float* __restrict__ cb, float* __restrict__ bc) {
  int e  = blockIdx.y;
  int cl = threadIdx.x & 63;
  int c  = blockIdx.x * 64 + cl;
  int ks = threadIdx.x >> 6;  // 4 k-slices
  float acc = 0.f;
  for (int k = ks; k < H_DIM; k += 4)
    acc += b2[e * H_DIM + k] * cw[(size_t)k * C_DIM + c];
  __shared__ float red[256];
  red[threadIdx.x] = acc;
  __syncthreads();
  if (ks == 0)
    bc[(size_t)e * C_DIM + c] = red[cl] + red[cl + 64] + red[cl + 128] + red[cl + 192] + cb[c];
}

// ---------------------------------------------------------------------------
extern "C" void kernel_launch(void* const* d_in, const int* in_sizes, int n_in,
                              void* d_out, int out_size, void* d_ws, size_t ws_size,
                              hipStream_t stream) {
  const float* x   = (const float*)d_in[0];
  const float* gw1 = (const float*)d_in[1];
  const float* gb1 = (const float*)d_in[2];
  const float* gw2 = (const float*)d_in[3];
  const float* gb2 = (const float*)d_in[4];
  const float* W1  = (const float*)d_in[5];
  const float* b1  = (const float*)d_in[6];
  const float* W2  = (const float*)d_in[7];
  const float* b2  = (const float*)d_in[8];
  const float* cw  = (const float*)d_in[9];
  const float* cb  = (const float*)d_in[10];

  char* ws = (char*)d_ws;
  _Float16* xb     = (_Float16*)(ws);                    // B*D        16 MB
  _Float16* g      = (_Float16*)(ws + 16777216ull);      // B*D        16 MB
  _Float16* gw1t   = (_Float16*)(ws + 33554432ull);      // D*D         2 MB
  _Float16* W1t    = (_Float16*)(ws + 35651584ull);      // E*H*D      32 MB
  _Float16* W2c    = (_Float16*)(ws + 69206016ull);      // E*H*H      64 MB (cast, NOT transposed)
  _Float16* cwt    = (_Float16*)(ws + 136314880ull);     // C*H         4 MB
  _Float16* WcombT = (_Float16*)(ws + 140509184ull);     // E*C*H      32 MB
  float*    bc     = (float*)   (ws + 174063616ull);     // E*C        32 KB
  _Float16* h_all  = (_Float16*)(ws + 174096384ull);     // E*B*H     256 MB
                                                         // total ~422 MB

  float* logits = (float*)d_out;
  float* scores = logits + (size_t)B_DIM * E_DIM * C_DIM;

  // Precision prep: casts + [N][K] weight transposes
  cast_f32_f16<<<B_DIM * D_DIM / 4 / 256, 256, 0, stream>>>(x, xb, B_DIM * D_DIM);
  transpose_cast<<<dim3(32, 32, 1), dim3(32, 8), 0, stream>>>(gw1, gw1t, D_DIM, D_DIM);
  transpose_cast<<<dim3(64, 32, 8), dim3(32, 8), 0, stream>>>(W1, W1t, D_DIM, H_DIM);
  cast_f32_f16<<<E_DIM * H_DIM * H_DIM / 4 / 256, 256, 0, stream>>>(W2, W2c, E_DIM * H_DIM * H_DIM);
  transpose_cast<<<dim3(32, 64, 1), dim3(32, 8), 0, stream>>>(cw, cwt, H_DIM, C_DIM);

  // Router (128^2 kernel: better grid fit at N=1024, M=8192 with 512 blocks)
  gemm_bt<true, true, _Float16><<<dim3(8, 64, 1), 256, 0, stream>>>(
      xb, 0, gw1t, 0, gb1, 0, g, 0, D_DIM, (long)D_DIM);
  gate2_softmax<<<B_DIM, 256, 0, stream>>>(g, gw2, gb2, scores);

  // Classifier folding: WcombT[e][c][h'] = sum_k2 Wc[k2][c] * W2[e][h'][k2]
  //   M=C=1024, N=H=2048, K=H=2048 -> grid (8,4,8) = 256 blocks, 1/CU.
  gemm256<false, false, _Float16, H_DIM><<<dim3(8, 4, 8), 512, 0, stream>>>(
      cwt, 0, W2c, (long)H_DIM * H_DIM, nullptr, 0,
      WcombT, (long)C_DIM * H_DIM, (long)H_DIM);
  combined_bias<<<dim3(C_DIM / 64, E_DIM), 256, 0, stream>>>(b2, cw, cb, bc);

  // Layer 1, all experts batched: h_all[e] = relu(x @ W1[e] + b1[e])
  gemm256<true, true, _Float16, D_DIM><<<dim3(8, 32, 8), 512, 0, stream>>>(
      xb, 0, W1t, (long)H_DIM * D_DIM, b1, (long)H_DIM,
      h_all, (long)B_DIM * H_DIM, (long)H_DIM);

  // Fused layer2+classifier: logits[:,e,:] = h_all[e] @ Wcomb[e] + bc[e]
  gemm256<false, true, float, H_DIM><<<dim3(4, 32, 8), 512, 0, stream>>>(
      h_all, (long)B_DIM * H_DIM, WcombT, (long)C_DIM * H_DIM, bc, (long)C_DIM,
      logits, (long)C_DIM, (long)(E_DIM * C_DIM));
}